// Round 1
// baseline (1162.457 us; speedup 1.0000x reference)
//
#include <hip/hip_runtime.h>
#include <math.h>

#define D_   512
#define H_   4
#define KC   128
#define T_   1024
#define B_   4
#define WIN_ 4
#define BAND 256
#define NEG_ -10000.0f

// ---------------------------------------------------------------------------
// GEMM: C = A * W^T + bias
//   A [M=4096, 512] row-major, W [512, 512] row-major ([out,in]), bias [512]
//   scatter=1: write q/k/v head-split layout [B,H,T,KC]
//   scatter=0: plain [M,512] row-major
// Tile: BM=128 x BN=64, BK=16, 256 threads, 8x4 per thread.
// ---------------------------------------------------------------------------
#define BM 128
#define BN 64
#define BK 16

__global__ __launch_bounds__(256) void gemm_bt(const float* __restrict__ A,
                                               const float* __restrict__ W,
                                               const float* __restrict__ bias,
                                               float* __restrict__ C,
                                               int scatter)
{
    __shared__ float As[BK][BM + 4];
    __shared__ float Ws[BK][BN + 4];

    const int tid = threadIdx.x;
    const int m0 = blockIdx.x * BM;
    const int n0 = blockIdx.y * BN;

    const int tx = tid & 15;   // col group: 4 cols
    const int ty = tid >> 4;   // row group: 8 rows

    const int lr = tid >> 2;         // 0..63 loader row
    const int lq = (tid & 3) * 4;    // 0,4,8,12 loader k-offset

    float acc[8][4];
#pragma unroll
    for (int i = 0; i < 8; i++)
#pragma unroll
        for (int j = 0; j < 4; j++) acc[i][j] = 0.f;

    for (int k0 = 0; k0 < D_; k0 += BK) {
        // stage A tile (128 x 16), transposed into As[k][m]
#pragma unroll
        for (int p = 0; p < 2; p++) {
            const int r = lr + p * 64;
            const float4 av = *(const float4*)(&A[(size_t)(m0 + r) * D_ + k0 + lq]);
            As[lq + 0][r] = av.x;
            As[lq + 1][r] = av.y;
            As[lq + 2][r] = av.z;
            As[lq + 3][r] = av.w;
        }
        // stage W tile (64 x 16), transposed into Ws[k][n]
        {
            const float4 wv = *(const float4*)(&W[(size_t)(n0 + lr) * D_ + k0 + lq]);
            Ws[lq + 0][lr] = wv.x;
            Ws[lq + 1][lr] = wv.y;
            Ws[lq + 2][lr] = wv.z;
            Ws[lq + 3][lr] = wv.w;
        }
        __syncthreads();

#pragma unroll
        for (int kk = 0; kk < BK; kk++) {
            const float4 a0 = *(const float4*)(&As[kk][ty * 8]);
            const float4 a1 = *(const float4*)(&As[kk][ty * 8 + 4]);
            const float4 w0 = *(const float4*)(&Ws[kk][tx * 4]);
            const float a[8] = {a0.x, a0.y, a0.z, a0.w, a1.x, a1.y, a1.z, a1.w};
            const float w[4] = {w0.x, w0.y, w0.z, w0.w};
#pragma unroll
            for (int i = 0; i < 8; i++)
#pragma unroll
                for (int j = 0; j < 4; j++) acc[i][j] += a[i] * w[j];
        }
        __syncthreads();
    }

    // epilogue
#pragma unroll
    for (int i = 0; i < 8; i++) {
        const int m = m0 + ty * 8 + i;
        const int b = m >> 10;          // m / T_
        const int t = m & (T_ - 1);     // m % T_
#pragma unroll
        for (int j = 0; j < 4; j++) {
            const int n = n0 + tx * 4 + j;
            const float val = acc[i][j] + bias[n];
            if (scatter) {
                const int h  = n >> 7;        // n / KC
                const int kc = n & (KC - 1);  // n % KC
                C[(size_t)(((b * H_ + h) * T_ + t)) * KC + kc] = val;
            } else {
                C[(size_t)m * D_ + n] = val;
            }
        }
    }
}

// ---------------------------------------------------------------------------
// Attention: one workgroup (256 threads) per (b,h,i) query row.
// Band |j-i| <= 256 (513 cols). Out-of-band entries are NEG -> exp underflows
// to exactly 0.0 in fp32 (same as numpy ref), so band-only softmax is exact.
// rel_k/rel_v contribute only for |j-i| <= 4 after _get_relative_embeddings
// padding (real rows land at relative offsets -4..+4).
// ---------------------------------------------------------------------------
__global__ __launch_bounds__(256) void attn_kernel(const float* __restrict__ q,
                                                   const float* __restrict__ k,
                                                   const float* __restrict__ v,
                                                   const float* __restrict__ mask,
                                                   const float* __restrict__ relk,
                                                   const float* __restrict__ relv,
                                                   float* __restrict__ out)
{
    const int n   = blockIdx.x;        // (b*H + h)*T + i
    const int i   = n & (T_ - 1);
    const int bh  = n >> 10;           // b*H + h
    const int b   = bh >> 2;
    const int h   = bh & 3;
    const int tid = threadIdx.x;

    const int jlo   = (i - BAND > 0) ? (i - BAND) : 0;
    const int jhi   = (i + BAND < T_ - 1) ? (i + BAND) : (T_ - 1);
    const int width = jhi - jlo + 1;

    __shared__ float qs[KC];
    __shared__ float ss[2 * BAND + 1];
    __shared__ float red[4];

    const float* qrow = q + ((size_t)bh * T_ + i) * KC;
    if (tid < KC) qs[tid] = qrow[tid];
    __syncthreads();

    const float scale = 0.08838834764831845f;  // 1/sqrt(128)
    const float mi = mask[b * T_ + i];

    // ---- scores over the band ----
    float lmax = -INFINITY;
    for (int idx = tid; idx < width; idx += 256) {
        const int j = jlo + idx;
        const float4* k4 = (const float4*)(k + ((size_t)bh * T_ + j) * KC);
        const float4* q4 = (const float4*)qs;
        float dot = 0.f;
#pragma unroll
        for (int kk = 0; kk < KC / 4; kk++) {
            const float4 kv = k4[kk];
            const float4 qv = q4[kk];
            dot += qv.x * kv.x + qv.y * kv.y + qv.z * kv.z + qv.w * kv.w;
        }
        const int d = j - i;
        float score = dot * scale;
        if (d >= -WIN_ && d <= WIN_) {
            const float4* r4 = (const float4*)(relk + (size_t)(d + WIN_) * KC);
            float rdot = 0.f;
#pragma unroll
            for (int kk = 0; kk < KC / 4; kk++) {
                const float4 rv = r4[kk];
                const float4 qv = q4[kk];
                rdot += qv.x * rv.x + qv.y * rv.y + qv.z * rv.z + qv.w * rv.w;
            }
            score += rdot * scale;
        }
        score -= log1pf(fabsf((float)d));
        if (mi == 0.f || mask[b * T_ + j] == 0.f) score = NEG_;
        ss[idx] = score;
        lmax = fmaxf(lmax, score);
    }

    // ---- block max ----
#pragma unroll
    for (int off = 32; off; off >>= 1) lmax = fmaxf(lmax, __shfl_xor(lmax, off));
    if ((tid & 63) == 0) red[tid >> 6] = lmax;
    __syncthreads();
    const float bmax = fmaxf(fmaxf(red[0], red[1]), fmaxf(red[2], red[3]));
    __syncthreads();

    // ---- exp + block sum ----
    float lsum = 0.f;
    for (int idx = tid; idx < width; idx += 256) {
        const float e = expf(ss[idx] - bmax);
        ss[idx] = e;
        lsum += e;
    }
#pragma unroll
    for (int off = 32; off; off >>= 1) lsum += __shfl_xor(lsum, off);
    if ((tid & 63) == 0) red[tid >> 6] = lsum;
    __syncthreads();
    const float inv = 1.f / (red[0] + red[1] + red[2] + red[3]);

    // ---- PV: 256 threads = 2 halves x 128 channels ----
    const int kk   = tid & 127;
    const int half = tid >> 7;
    const int wh   = (width + 1) >> 1;
    const int lo   = half * wh;
    const int hi   = (lo + wh < width) ? (lo + wh) : width;

    const float* vbase = v + ((size_t)bh * T_ + jlo) * KC + kk;
    float a0 = 0.f, a1 = 0.f, a2 = 0.f, a3 = 0.f;
    int idx = lo;
    for (; idx + 3 < hi; idx += 4) {
        a0 += ss[idx + 0] * vbase[(size_t)(idx + 0) * KC];
        a1 += ss[idx + 1] * vbase[(size_t)(idx + 1) * KC];
        a2 += ss[idx + 2] * vbase[(size_t)(idx + 2) * KC];
        a3 += ss[idx + 3] * vbase[(size_t)(idx + 3) * KC];
    }
    for (; idx < hi; idx++) a0 += ss[idx] * vbase[(size_t)idx * KC];
    float accp = (a0 + a1) + (a2 + a3);

    if (half) qs[kk] = accp;
    __syncthreads();
    if (!half) {
        float acc = (accp + qs[kk]) * inv;
        // relative-value contribution: p[i, i+d] * relv[d+4]
#pragma unroll
        for (int d = -WIN_; d <= WIN_; d++) {
            const int j = i + d;
            if (j >= 0 && j < T_) acc += (ss[j - jlo] * inv) * relv[(size_t)(d + WIN_) * KC + kk];
        }
        out[((size_t)(b * T_ + i) * H_ + h) * KC + kk] = acc;
    }
}

// ---------------------------------------------------------------------------
extern "C" void kernel_launch(void* const* d_in, const int* in_sizes, int n_in,
                              void* d_out, int out_size, void* d_ws, size_t ws_size,
                              hipStream_t stream)
{
    const float* x    = (const float*)d_in[0];
    const float* c    = (const float*)d_in[1];
    const float* am   = (const float*)d_in[2];
    const float* Wq   = (const float*)d_in[3];
    const float* bq   = (const float*)d_in[4];
    const float* Wk   = (const float*)d_in[5];
    const float* bk   = (const float*)d_in[6];
    const float* Wv   = (const float*)d_in[7];
    const float* bv   = (const float*)d_in[8];
    const float* Wo   = (const float*)d_in[9];
    const float* bo   = (const float*)d_in[10];
    const float* relk = (const float*)d_in[11];
    const float* relv = (const float*)d_in[12];

    float* out  = (float*)d_out;
    float* ws   = (float*)d_ws;
    const size_t SZ = (size_t)B_ * H_ * T_ * KC;  // 2,097,152 floats = 8 MB
    float* q    = ws;
    float* k    = ws + SZ;
    float* v    = ws + 2 * SZ;
    float* attn = ws + 3 * SZ;

    dim3 ggrid(4096 / BM, D_ / BN);  // (32, 8)
    gemm_bt<<<ggrid, 256, 0, stream>>>(x, Wq, bq, q, 1);
    gemm_bt<<<ggrid, 256, 0, stream>>>(c, Wk, bk, k, 1);
    gemm_bt<<<ggrid, 256, 0, stream>>>(c, Wv, bv, v, 1);

    attn_kernel<<<B_ * H_ * T_, 256, 0, stream>>>(q, k, v, am, relk, relv, attn);

    gemm_bt<<<ggrid, 256, 0, stream>>>(attn, Wo, bo, out, 0);
}

// Round 2
// 461.992 us; speedup vs baseline: 2.5162x; 2.5162x over previous
//
#include <hip/hip_runtime.h>
#include <math.h>

#define D_   512
#define H_   4
#define KC   128
#define T_   1024
#define B_   4
#define WIN_ 4
#define BAND 256
#define NEG_ -10000.0f

// ---------------------------------------------------------------------------
// GEMM: C = A * W^T + bias   (unchanged from R1)
// ---------------------------------------------------------------------------
#define BM 128
#define BN 64
#define BK 16

__global__ __launch_bounds__(256) void gemm_bt(const float* __restrict__ A,
                                               const float* __restrict__ W,
                                               const float* __restrict__ bias,
                                               float* __restrict__ C,
                                               int scatter)
{
    __shared__ float As[BK][BM + 4];
    __shared__ float Ws[BK][BN + 4];

    const int tid = threadIdx.x;
    const int m0 = blockIdx.x * BM;
    const int n0 = blockIdx.y * BN;

    const int tx = tid & 15;
    const int ty = tid >> 4;

    const int lr = tid >> 2;
    const int lq = (tid & 3) * 4;

    float acc[8][4];
#pragma unroll
    for (int i = 0; i < 8; i++)
#pragma unroll
        for (int j = 0; j < 4; j++) acc[i][j] = 0.f;

    for (int k0 = 0; k0 < D_; k0 += BK) {
#pragma unroll
        for (int p = 0; p < 2; p++) {
            const int r = lr + p * 64;
            const float4 av = *(const float4*)(&A[(size_t)(m0 + r) * D_ + k0 + lq]);
            As[lq + 0][r] = av.x;
            As[lq + 1][r] = av.y;
            As[lq + 2][r] = av.z;
            As[lq + 3][r] = av.w;
        }
        {
            const float4 wv = *(const float4*)(&W[(size_t)(n0 + lr) * D_ + k0 + lq]);
            Ws[lq + 0][lr] = wv.x;
            Ws[lq + 1][lr] = wv.y;
            Ws[lq + 2][lr] = wv.z;
            Ws[lq + 3][lr] = wv.w;
        }
        __syncthreads();

#pragma unroll
        for (int kk = 0; kk < BK; kk++) {
            const float4 a0 = *(const float4*)(&As[kk][ty * 8]);
            const float4 a1 = *(const float4*)(&As[kk][ty * 8 + 4]);
            const float4 w0 = *(const float4*)(&Ws[kk][tx * 4]);
            const float a[8] = {a0.x, a0.y, a0.z, a0.w, a1.x, a1.y, a1.z, a1.w};
            const float w[4] = {w0.x, w0.y, w0.z, w0.w};
#pragma unroll
            for (int i = 0; i < 8; i++)
#pragma unroll
                for (int j = 0; j < 4; j++) acc[i][j] += a[i] * w[j];
        }
        __syncthreads();
    }

#pragma unroll
    for (int i = 0; i < 8; i++) {
        const int m = m0 + ty * 8 + i;
        const int b = m >> 10;
        const int t = m & (T_ - 1);
#pragma unroll
        for (int j = 0; j < 4; j++) {
            const int n = n0 + tx * 4 + j;
            const float val = acc[i][j] + bias[n];
            if (scatter) {
                const int h  = n >> 7;
                const int kc = n & (KC - 1);
                C[(size_t)(((b * H_ + h) * T_ + t)) * KC + kc] = val;
            } else {
                C[(size_t)m * D_ + n] = val;
            }
        }
    }
}

// ---------------------------------------------------------------------------
// Tiled flash-style attention.
// Block = 256 threads, handles (b,h) x 64-row Q-tile. Col tiles of 64 over
// the band union [i0-256, i0+64+256) (tile-aligned -> all tiles full).
// Thread tile: S-phase 4 rows x 4 cols; PV-phase 4 rows x 8 channels (same
// row ownership, so online-softmax state stays in registers).
// ---------------------------------------------------------------------------
#define TQ 64
#define TC 64

__global__ __launch_bounds__(256) void attn_tiled(const float* __restrict__ q,
                                                  const float* __restrict__ k,
                                                  const float* __restrict__ v,
                                                  const float* __restrict__ mask,
                                                  const float* __restrict__ relk,
                                                  const float* __restrict__ relv,
                                                  float* __restrict__ out)
{
    const int bh = blockIdx.y;
    const int b  = bh >> 2;
    const int h  = bh & 3;
    const int i0 = blockIdx.x * TQ;
    const int tid = threadIdx.x;
    const int tx = tid & 15;
    const int ty = tid >> 4;

    __shared__ __align__(16) float Qs[KC][TQ + 4];   // 34816 B (transposed)
    __shared__ __align__(16) float Ks[KC][TC + 4];   // 34816 B (transposed)
    __shared__ __align__(16) float Vs[TC][KC + 4];   // 33792 B (direct)
    __shared__ __align__(16) float Ps[TQ][TC + 4];   // 17408 B
    __shared__ float rlog[TQ][9];
    __shared__ float pdiag[TQ][9];
    __shared__ float msk[TC];
    __shared__ float rowm[TQ];

    const float scale = 0.08838834764831845f;  // 1/sqrt(128)

    // ---- stage Q tile (transposed), row mask, zero pdiag ----
    const float* qbase = q + (size_t)(bh * T_ + i0) * KC;
#pragma unroll
    for (int u = 0; u < 8; u++) {
        const int e = u * 256 + tid;
        const int r = e >> 5;
        const int kq = (e & 31) * 4;
        const float4 val = *(const float4*)(qbase + (size_t)r * KC + kq);
        Qs[kq + 0][r] = val.x;
        Qs[kq + 1][r] = val.y;
        Qs[kq + 2][r] = val.z;
        Qs[kq + 3][r] = val.w;
    }
    if (tid < TQ) rowm[tid] = mask[b * T_ + i0 + tid];
    for (int e = tid; e < TQ * 9; e += 256) ((float*)pdiag)[e] = 0.f;
    __syncthreads();

    // ---- rel-k logits: rlog[r][d] = scale * q[i0+r] . relk[d] ----
    {
        const int r = tid >> 2;          // 0..63
        const int kq4 = tid & 3;         // quarter of K
#pragma unroll
        for (int d = 0; d < 9; d++) {
            float s = 0.f;
            const int kbeg = kq4 * 32;
            for (int kk = kbeg; kk < kbeg + 32; kk++)
                s += Qs[kk][r] * relk[d * KC + kk];
            s += __shfl_xor(s, 1);
            s += __shfl_xor(s, 2);
            if (kq4 == 0) rlog[r][d] = s * scale;
        }
    }
    // rlog becomes visible at the top-of-loop barrier of tile 0.

    float m_run[4], l_run[4], O[4][8];
#pragma unroll
    for (int rr = 0; rr < 4; rr++) {
        m_run[rr] = -1e30f;
        l_run[rr] = 0.f;
#pragma unroll
        for (int c = 0; c < 8; c++) O[rr][c] = 0.f;
    }

    const int cstart = (i0 - BAND > 0) ? (i0 - BAND) : 0;
    const int cend   = (i0 + TQ + BAND < T_) ? (i0 + TQ + BAND) : T_;
    const int nt     = (cend - cstart) >> 6;
    const int vcol   = tx * 8;

    for (int t = 0; t < nt; t++) {
        const int j0 = cstart + t * TC;
        __syncthreads();  // (1) prior tile's S/PV/pdiag-adds done

        // ---- stage K (transposed) + V (direct) + col mask ----
        const float* kb = k + (size_t)(bh * T_ + j0) * KC;
        const float* vb = v + (size_t)(bh * T_ + j0) * KC;
#pragma unroll
        for (int u = 0; u < 8; u++) {
            const int e = u * 256 + tid;
            const int r = e >> 5;
            const int kq = (e & 31) * 4;
            const float4 kv = *(const float4*)(kb + (size_t)r * KC + kq);
            Ks[kq + 0][r] = kv.x;
            Ks[kq + 1][r] = kv.y;
            Ks[kq + 2][r] = kv.z;
            Ks[kq + 3][r] = kv.w;
            const float4 vv = *(const float4*)(vb + (size_t)r * KC + kq);
            *(float4*)&Vs[r][kq] = vv;
        }
        if (tid < TC) msk[tid] = mask[b * T_ + j0 + tid];
        __syncthreads();  // (2)

        // ---- S = Q . K^T  (4x4 per thread) ----
        float acc[4][4];
#pragma unroll
        for (int rr = 0; rr < 4; rr++)
#pragma unroll
            for (int cc = 0; cc < 4; cc++) acc[rr][cc] = 0.f;

#pragma unroll 8
        for (int kk = 0; kk < KC; kk++) {
            const float4 a = *(const float4*)&Qs[kk][ty * 4];
            const float4 bb = *(const float4*)&Ks[kk][tx * 4];
            const float av[4] = {a.x, a.y, a.z, a.w};
            const float bv4[4] = {bb.x, bb.y, bb.z, bb.w};
#pragma unroll
            for (int rr = 0; rr < 4; rr++)
#pragma unroll
                for (int cc = 0; cc < 4; cc++) acc[rr][cc] += av[rr] * bv4[cc];
        }

        // ---- score fixup + online softmax ----
        float alpha[4];
#pragma unroll
        for (int rr = 0; rr < 4; rr++) {
            const int r = ty * 4 + rr;
            const int i = i0 + r;
            const float rm = rowm[r];
            float mt = -1e30f;
#pragma unroll
            for (int cc = 0; cc < 4; cc++) {
                const int j = j0 + tx * 4 + cc;
                const int d = j - i;
                float s;
                if (rm != 0.f && msk[j - j0] != 0.f && d >= -BAND && d <= BAND) {
                    s = acc[rr][cc] * scale - log1pf(fabsf((float)d));
                    if (d >= -WIN_ && d <= WIN_) s += rlog[r][d + WIN_];
                } else {
                    s = NEG_;
                }
                acc[rr][cc] = s;
                mt = fmaxf(mt, s);
            }
            mt = fmaxf(mt, __shfl_xor(mt, 1));
            mt = fmaxf(mt, __shfl_xor(mt, 2));
            mt = fmaxf(mt, __shfl_xor(mt, 4));
            mt = fmaxf(mt, __shfl_xor(mt, 8));
            const float mnew = fmaxf(m_run[rr], mt);
            alpha[rr] = expf(m_run[rr] - mnew);
            m_run[rr] = mnew;

            float lt = 0.f;
#pragma unroll
            for (int cc = 0; cc < 4; cc++) {
                const float p = expf(acc[rr][cc] - mnew);
                acc[rr][cc] = p;
                lt += p;
            }
            *(float4*)&Ps[r][tx * 4] =
                make_float4(acc[rr][0], acc[rr][1], acc[rr][2], acc[rr][3]);
            lt += __shfl_xor(lt, 1);
            lt += __shfl_xor(lt, 2);
            lt += __shfl_xor(lt, 4);
            lt += __shfl_xor(lt, 8);
            l_run[rr] = l_run[rr] * alpha[rr] + lt;

            // tx==0 lane owns the pdiag rescale for its 4 rows (alpha in reg)
            if (tx == 0) {
#pragma unroll
                for (int d = 0; d < 9; d++) pdiag[r][d] *= alpha[rr];
            }
        }
        __syncthreads();  // (3) Ps + pdiag-rescale visible

        // ---- pdiag adds (unique owner per (row, d)) ----
#pragma unroll
        for (int rr = 0; rr < 4; rr++) {
            const int r = ty * 4 + rr;
            const int i = i0 + r;
#pragma unroll
            for (int cc = 0; cc < 4; cc++) {
                const int d = (j0 + tx * 4 + cc) - i;
                if (d >= -WIN_ && d <= WIN_) pdiag[r][d + WIN_] += acc[rr][cc];
            }
        }

        // ---- PV: O = O*alpha + P . V  (4 rows x 8 channels) ----
#pragma unroll
        for (int rr = 0; rr < 4; rr++)
#pragma unroll
            for (int c = 0; c < 8; c++) O[rr][c] *= alpha[rr];

#pragma unroll 2
        for (int jj = 0; jj < TC; jj += 4) {
            float pra[4][4];
#pragma unroll
            for (int rr = 0; rr < 4; rr++) {
                const float4 pr = *(const float4*)&Ps[ty * 4 + rr][jj];
                pra[rr][0] = pr.x; pra[rr][1] = pr.y; pra[rr][2] = pr.z; pra[rr][3] = pr.w;
            }
#pragma unroll
            for (int js = 0; js < 4; js++) {
                const float4 va = *(const float4*)&Vs[jj + js][vcol];
                const float4 vb2 = *(const float4*)&Vs[jj + js][vcol + 4];
                const float vv[8] = {va.x, va.y, va.z, va.w, vb2.x, vb2.y, vb2.z, vb2.w};
#pragma unroll
                for (int rr = 0; rr < 4; rr++) {
                    const float pj = pra[rr][js];
#pragma unroll
                    for (int c = 0; c < 8; c++) O[rr][c] += pj * vv[c];
                }
            }
        }
    }

    __syncthreads();  // final pdiag adds visible

    // ---- epilogue: add rel-v contribution, normalize, store ----
#pragma unroll
    for (int rr = 0; rr < 4; rr++) {
        const int r = ty * 4 + rr;
        const int i = i0 + r;
        const float invl = 1.f / l_run[rr];
        float o[8];
#pragma unroll
        for (int c = 0; c < 8; c++) o[c] = O[rr][c];
#pragma unroll
        for (int d = 0; d < 9; d++) {
            const int j = i + d - WIN_;
            if (j >= 0 && j < T_) {
                const float pd = pdiag[r][d];
#pragma unroll
                for (int c = 0; c < 8; c++) o[c] += pd * relv[d * KC + vcol + c];
            }
        }
        float* ob = out + ((size_t)(b * T_ + i) * H_ + h) * KC + vcol;
        *(float4*)ob = make_float4(o[0] * invl, o[1] * invl, o[2] * invl, o[3] * invl);
        *(float4*)(ob + 4) = make_float4(o[4] * invl, o[5] * invl, o[6] * invl, o[7] * invl);
    }
}

// ---------------------------------------------------------------------------
extern "C" void kernel_launch(void* const* d_in, const int* in_sizes, int n_in,
                              void* d_out, int out_size, void* d_ws, size_t ws_size,
                              hipStream_t stream)
{
    const float* x    = (const float*)d_in[0];
    const float* c    = (const float*)d_in[1];
    const float* am   = (const float*)d_in[2];
    const float* Wq   = (const float*)d_in[3];
    const float* bq   = (const float*)d_in[4];
    const float* Wk   = (const float*)d_in[5];
    const float* bk   = (const float*)d_in[6];
    const float* Wv   = (const float*)d_in[7];
    const float* bv   = (const float*)d_in[8];
    const float* Wo   = (const float*)d_in[9];
    const float* bo   = (const float*)d_in[10];
    const float* relk = (const float*)d_in[11];
    const float* relv = (const float*)d_in[12];

    float* out  = (float*)d_out;
    float* ws   = (float*)d_ws;
    const size_t SZ = (size_t)B_ * H_ * T_ * KC;
    float* q    = ws;
    float* k    = ws + SZ;
    float* v    = ws + 2 * SZ;
    float* attn = ws + 3 * SZ;

    dim3 ggrid(4096 / BM, D_ / BN);
    gemm_bt<<<ggrid, 256, 0, stream>>>(x, Wq, bq, q, 1);
    gemm_bt<<<ggrid, 256, 0, stream>>>(c, Wk, bk, k, 1);
    gemm_bt<<<ggrid, 256, 0, stream>>>(c, Wv, bv, v, 1);

    attn_tiled<<<dim3(T_ / TQ, B_ * H_), 256, 0, stream>>>(q, k, v, am, relk, relv, attn);

    gemm_bt<<<ggrid, 256, 0, stream>>>(attn, Wo, bo, out, 0);
}

// Round 3
// 299.398 us; speedup vs baseline: 3.8826x; 1.5431x over previous
//
#include <hip/hip_runtime.h>
#include <math.h>

#define D_   512
#define H_   4
#define KC   128
#define T_   1024
#define B_   4
#define WIN_ 4
#define BAND 256
#define NEG_ -10000.0f

typedef short bf16x8 __attribute__((ext_vector_type(8)));
typedef float f32x4  __attribute__((ext_vector_type(4)));

__device__ __forceinline__ ushort f2b_rne(float x) {
    unsigned u = __float_as_uint(x);
    u += 0x7fffu + ((u >> 16) & 1u);
    return (ushort)(u >> 16);
}
__device__ __forceinline__ float b2f_lo(unsigned u) { return __uint_as_float(u << 16); }
__device__ __forceinline__ float b2f_hi(unsigned u) { return __uint_as_float(u & 0xffff0000u); }

// ---------------------------------------------------------------------------
// fp32 -> bf16 (RNE) converter, 8 elems/thread
// ---------------------------------------------------------------------------
__global__ __launch_bounds__(256) void cvt_f2b(const float* __restrict__ in,
                                               ushort* __restrict__ out, int n8)
{
    const int i = blockIdx.x * 256 + threadIdx.x;
    if (i >= n8) return;
    const float4 a = ((const float4*)in)[2 * i];
    const float4 b = ((const float4*)in)[2 * i + 1];
    uint4 r;
    r.x = (unsigned)f2b_rne(a.x) | ((unsigned)f2b_rne(a.y) << 16);
    r.y = (unsigned)f2b_rne(a.z) | ((unsigned)f2b_rne(a.w) << 16);
    r.z = (unsigned)f2b_rne(b.x) | ((unsigned)f2b_rne(b.y) << 16);
    r.w = (unsigned)f2b_rne(b.z) | ((unsigned)f2b_rne(b.w) << 16);
    ((uint4*)out)[i] = r;
}

// ---------------------------------------------------------------------------
// bf16 MFMA GEMM: C = A * W^T + bias
//   A [4096,512] bf16 row-major (K-contig), W [512,512] bf16 row-major ([out,in])
//   scatter=1: write bf16 to q/k/v head-split layout [B,H,T,KC]
//   scatter=0: write fp32 row-major [M,512]
// Tile 64x64, BK=32, 256 threads = 4 waves (2x2), wave tile 32x32 via
// 2x2 mfma_f32_16x16x32_bf16. global_load_lds width=16 staging.
// ---------------------------------------------------------------------------
#define GB 64
#define GK 32

__global__ __launch_bounds__(256) void gemm_mfma(const ushort* __restrict__ A,
                                                 const ushort* __restrict__ W,
                                                 const float* __restrict__ bias,
                                                 void* __restrict__ Cout, int scatter)
{
    __shared__ __align__(16) ushort As[GB * GK];  // [row][k] row-major, 4 KB
    __shared__ __align__(16) ushort Bs[GB * GK];

    const int tid = threadIdx.x;
    const int m0 = blockIdx.x * GB;
    const int n0 = blockIdx.y * GB;
    const int lane = tid & 63;
    const int wid  = tid >> 6;
    const int wm = (wid >> 1) * 32;
    const int wn = (wid & 1) * 32;

    // staging: thread t owns 16B chunk t: row = t>>2, kchunk = t&3
    const int srow = tid >> 2;
    const int skb  = (tid & 3) * 8;
    const ushort* ga = A + (size_t)(m0 + srow) * D_ + skb;
    const ushort* gb = W + (size_t)(n0 + srow) * D_ + skb;

    f32x4 acc[2][2] = {};

    const int frow = lane & 15;   // m (A) / n (B) within 16-tile
    const int fq   = lane >> 4;   // quad -> k chunk

    for (int k0 = 0; k0 < D_; k0 += GK) {
        __syncthreads();
        __builtin_amdgcn_global_load_lds(
            (const __attribute__((address_space(1))) void*)(ga + k0),
            (__attribute__((address_space(3))) void*)(As + tid * 8), 16, 0, 0);
        __builtin_amdgcn_global_load_lds(
            (const __attribute__((address_space(1))) void*)(gb + k0),
            (__attribute__((address_space(3))) void*)(Bs + tid * 8), 16, 0, 0);
        __syncthreads();

        bf16x8 af[2], bf[2];
#pragma unroll
        for (int mt = 0; mt < 2; mt++)
            af[mt] = *(const bf16x8*)(As + ((wm + mt * 16 + frow) * 4 + fq) * 8);
#pragma unroll
        for (int nt = 0; nt < 2; nt++)
            bf[nt] = *(const bf16x8*)(Bs + ((wn + nt * 16 + frow) * 4 + fq) * 8);
#pragma unroll
        for (int mt = 0; mt < 2; mt++)
#pragma unroll
            for (int nt = 0; nt < 2; nt++)
                acc[mt][nt] = __builtin_amdgcn_mfma_f32_16x16x32_bf16(
                    af[mt], bf[nt], acc[mt][nt], 0, 0, 0);
    }

    // epilogue: C/D layout col = lane&15 (n), row = quad*4+reg (m)
#pragma unroll
    for (int mt = 0; mt < 2; mt++)
#pragma unroll
        for (int nt = 0; nt < 2; nt++) {
            const int n = n0 + wn + nt * 16 + frow;
            const float bn = bias[n];
#pragma unroll
            for (int r = 0; r < 4; r++) {
                const int m = m0 + wm + mt * 16 + fq * 4 + r;
                const float val = acc[mt][nt][r] + bn;
                if (scatter) {
                    const int b = m >> 10, t = m & (T_ - 1);
                    const int h = n >> 7, kc = n & (KC - 1);
                    ((ushort*)Cout)[((size_t)((b * H_ + h) * T_ + t)) * KC + kc] = f2b_rne(val);
                } else {
                    ((float*)Cout)[(size_t)m * D_ + n] = val;
                }
            }
        }
}

// ---------------------------------------------------------------------------
// Tiled flash-style attention (fp32 math, bf16 in/out).
// ---------------------------------------------------------------------------
#define TQ 64
#define TC 64

__global__ __launch_bounds__(256) void attn_tiled(const ushort* __restrict__ q,
                                                  const ushort* __restrict__ k,
                                                  const ushort* __restrict__ v,
                                                  const float* __restrict__ mask,
                                                  const float* __restrict__ relk,
                                                  const float* __restrict__ relv,
                                                  ushort* __restrict__ out)
{
    const int bh = blockIdx.y;
    const int b  = bh >> 2;
    const int h  = bh & 3;
    const int i0 = blockIdx.x * TQ;
    const int tid = threadIdx.x;
    const int tx = tid & 15;
    const int ty = tid >> 4;

    __shared__ __align__(16) float Qs[KC][TQ + 4];
    __shared__ __align__(16) float Ks[KC][TC + 4];
    __shared__ __align__(16) float Vs[TC][KC + 4];
    __shared__ __align__(16) float Ps[TQ][TC + 4];
    __shared__ float rlog[TQ][9];
    __shared__ float pdiag[TQ][9];
    __shared__ float msk[TC];
    __shared__ float rowm[TQ];

    const float scale = 0.08838834764831845f;  // 1/sqrt(128)

    // ---- stage Q tile (bf16 -> fp32, transposed) ----
    const ushort* qbase = q + (size_t)(bh * T_ + i0) * KC;
#pragma unroll
    for (int u = 0; u < 4; u++) {
        const int e = u * 256 + tid;     // 0..1023
        const int r = e >> 4;
        const int kq = (e & 15) * 8;
        const uint4 raw = *(const uint4*)(qbase + (size_t)r * KC + kq);
        Qs[kq + 0][r] = b2f_lo(raw.x);
        Qs[kq + 1][r] = b2f_hi(raw.x);
        Qs[kq + 2][r] = b2f_lo(raw.y);
        Qs[kq + 3][r] = b2f_hi(raw.y);
        Qs[kq + 4][r] = b2f_lo(raw.z);
        Qs[kq + 5][r] = b2f_hi(raw.z);
        Qs[kq + 6][r] = b2f_lo(raw.w);
        Qs[kq + 7][r] = b2f_hi(raw.w);
    }
    if (tid < TQ) rowm[tid] = mask[b * T_ + i0 + tid];
    for (int e = tid; e < TQ * 9; e += 256) ((float*)pdiag)[e] = 0.f;
    __syncthreads();

    // ---- rel-k logits ----
    {
        const int r = tid >> 2;
        const int kq4 = tid & 3;
#pragma unroll
        for (int d = 0; d < 9; d++) {
            float s = 0.f;
            const int kbeg = kq4 * 32;
            for (int kk = kbeg; kk < kbeg + 32; kk++)
                s += Qs[kk][r] * relk[d * KC + kk];
            s += __shfl_xor(s, 1);
            s += __shfl_xor(s, 2);
            if (kq4 == 0) rlog[r][d] = s * scale;
        }
    }

    float m_run[4], l_run[4], O[4][8];
#pragma unroll
    for (int rr = 0; rr < 4; rr++) {
        m_run[rr] = -1e30f;
        l_run[rr] = 0.f;
#pragma unroll
        for (int c = 0; c < 8; c++) O[rr][c] = 0.f;
    }

    const int cstart = (i0 - BAND > 0) ? (i0 - BAND) : 0;
    const int cend   = (i0 + TQ + BAND < T_) ? (i0 + TQ + BAND) : T_;
    const int nt     = (cend - cstart) >> 6;
    const int vcol   = tx * 8;

    for (int t = 0; t < nt; t++) {
        const int j0 = cstart + t * TC;
        __syncthreads();  // (1)

        const ushort* kb = k + (size_t)(bh * T_ + j0) * KC;
        const ushort* vb = v + (size_t)(bh * T_ + j0) * KC;
#pragma unroll
        for (int u = 0; u < 4; u++) {
            const int e = u * 256 + tid;
            const int r = e >> 4;
            const int kq = (e & 15) * 8;
            const uint4 kr = *(const uint4*)(kb + (size_t)r * KC + kq);
            Ks[kq + 0][r] = b2f_lo(kr.x);
            Ks[kq + 1][r] = b2f_hi(kr.x);
            Ks[kq + 2][r] = b2f_lo(kr.y);
            Ks[kq + 3][r] = b2f_hi(kr.y);
            Ks[kq + 4][r] = b2f_lo(kr.z);
            Ks[kq + 5][r] = b2f_hi(kr.z);
            Ks[kq + 6][r] = b2f_lo(kr.w);
            Ks[kq + 7][r] = b2f_hi(kr.w);
            const uint4 vr = *(const uint4*)(vb + (size_t)r * KC + kq);
            *(float4*)&Vs[r][kq]     = make_float4(b2f_lo(vr.x), b2f_hi(vr.x), b2f_lo(vr.y), b2f_hi(vr.y));
            *(float4*)&Vs[r][kq + 4] = make_float4(b2f_lo(vr.z), b2f_hi(vr.z), b2f_lo(vr.w), b2f_hi(vr.w));
        }
        if (tid < TC) msk[tid] = mask[b * T_ + j0 + tid];
        __syncthreads();  // (2)

        // ---- S = Q . K^T ----
        float acc[4][4];
#pragma unroll
        for (int rr = 0; rr < 4; rr++)
#pragma unroll
            for (int cc = 0; cc < 4; cc++) acc[rr][cc] = 0.f;

#pragma unroll 8
        for (int kk = 0; kk < KC; kk++) {
            const float4 a = *(const float4*)&Qs[kk][ty * 4];
            const float4 bb = *(const float4*)&Ks[kk][tx * 4];
            const float av[4] = {a.x, a.y, a.z, a.w};
            const float bv4[4] = {bb.x, bb.y, bb.z, bb.w};
#pragma unroll
            for (int rr = 0; rr < 4; rr++)
#pragma unroll
                for (int cc = 0; cc < 4; cc++) acc[rr][cc] += av[rr] * bv4[cc];
        }

        // ---- score fixup + online softmax ----
        float alpha[4];
#pragma unroll
        for (int rr = 0; rr < 4; rr++) {
            const int r = ty * 4 + rr;
            const int i = i0 + r;
            const float rm = rowm[r];
            float mt = -1e30f;
#pragma unroll
            for (int cc = 0; cc < 4; cc++) {
                const int j = j0 + tx * 4 + cc;
                const int d = j - i;
                float s;
                if (rm != 0.f && msk[j - j0] != 0.f && d >= -BAND && d <= BAND) {
                    s = acc[rr][cc] * scale - log1pf(fabsf((float)d));
                    if (d >= -WIN_ && d <= WIN_) s += rlog[r][d + WIN_];
                } else {
                    s = NEG_;
                }
                acc[rr][cc] = s;
                mt = fmaxf(mt, s);
            }
            mt = fmaxf(mt, __shfl_xor(mt, 1));
            mt = fmaxf(mt, __shfl_xor(mt, 2));
            mt = fmaxf(mt, __shfl_xor(mt, 4));
            mt = fmaxf(mt, __shfl_xor(mt, 8));
            const float mnew = fmaxf(m_run[rr], mt);
            alpha[rr] = expf(m_run[rr] - mnew);
            m_run[rr] = mnew;

            float lt = 0.f;
#pragma unroll
            for (int cc = 0; cc < 4; cc++) {
                const float p = expf(acc[rr][cc] - mnew);
                acc[rr][cc] = p;
                lt += p;
            }
            *(float4*)&Ps[r][tx * 4] =
                make_float4(acc[rr][0], acc[rr][1], acc[rr][2], acc[rr][3]);
            lt += __shfl_xor(lt, 1);
            lt += __shfl_xor(lt, 2);
            lt += __shfl_xor(lt, 4);
            lt += __shfl_xor(lt, 8);
            l_run[rr] = l_run[rr] * alpha[rr] + lt;

            if (tx == 0) {
#pragma unroll
                for (int d = 0; d < 9; d++) pdiag[r][d] *= alpha[rr];
            }
        }
        __syncthreads();  // (3)

        // ---- pdiag adds ----
#pragma unroll
        for (int rr = 0; rr < 4; rr++) {
            const int r = ty * 4 + rr;
            const int i = i0 + r;
#pragma unroll
            for (int cc = 0; cc < 4; cc++) {
                const int d = (j0 + tx * 4 + cc) - i;
                if (d >= -WIN_ && d <= WIN_) pdiag[r][d + WIN_] += acc[rr][cc];
            }
        }

        // ---- PV ----
#pragma unroll
        for (int rr = 0; rr < 4; rr++)
#pragma unroll
            for (int c = 0; c < 8; c++) O[rr][c] *= alpha[rr];

#pragma unroll 2
        for (int jj = 0; jj < TC; jj += 4) {
            float pra[4][4];
#pragma unroll
            for (int rr = 0; rr < 4; rr++) {
                const float4 pr = *(const float4*)&Ps[ty * 4 + rr][jj];
                pra[rr][0] = pr.x; pra[rr][1] = pr.y; pra[rr][2] = pr.z; pra[rr][3] = pr.w;
            }
#pragma unroll
            for (int js = 0; js < 4; js++) {
                const float4 va = *(const float4*)&Vs[jj + js][vcol];
                const float4 vb2 = *(const float4*)&Vs[jj + js][vcol + 4];
                const float vv[8] = {va.x, va.y, va.z, va.w, vb2.x, vb2.y, vb2.z, vb2.w};
#pragma unroll
                for (int rr = 0; rr < 4; rr++) {
                    const float pj = pra[rr][js];
#pragma unroll
                    for (int c = 0; c < 8; c++) O[rr][c] += pj * vv[c];
                }
            }
        }
    }

    __syncthreads();

    // ---- epilogue: rel-v, normalize, store bf16 ----
#pragma unroll
    for (int rr = 0; rr < 4; rr++) {
        const int r = ty * 4 + rr;
        const int i = i0 + r;
        const float invl = 1.f / l_run[rr];
        float o[8];
#pragma unroll
        for (int c = 0; c < 8; c++) o[c] = O[rr][c];
#pragma unroll
        for (int d = 0; d < 9; d++) {
            const int j = i + d - WIN_;
            if (j >= 0 && j < T_) {
                const float pd = pdiag[r][d];
#pragma unroll
                for (int c = 0; c < 8; c++) o[c] += pd * relv[d * KC + vcol + c];
            }
        }
        ushort* ob = out + (((size_t)(b * T_ + i) * H_ + h) * KC + vcol);
        uint4 w;
        w.x = (unsigned)f2b_rne(o[0] * invl) | ((unsigned)f2b_rne(o[1] * invl) << 16);
        w.y = (unsigned)f2b_rne(o[2] * invl) | ((unsigned)f2b_rne(o[3] * invl) << 16);
        w.z = (unsigned)f2b_rne(o[4] * invl) | ((unsigned)f2b_rne(o[5] * invl) << 16);
        w.w = (unsigned)f2b_rne(o[6] * invl) | ((unsigned)f2b_rne(o[7] * invl) << 16);
        *(uint4*)ob = w;
    }
}

// ---------------------------------------------------------------------------
extern "C" void kernel_launch(void* const* d_in, const int* in_sizes, int n_in,
                              void* d_out, int out_size, void* d_ws, size_t ws_size,
                              hipStream_t stream)
{
    const float* x    = (const float*)d_in[0];
    const float* c    = (const float*)d_in[1];
    const float* am   = (const float*)d_in[2];
    const float* Wq   = (const float*)d_in[3];
    const float* bq   = (const float*)d_in[4];
    const float* Wk   = (const float*)d_in[5];
    const float* bk   = (const float*)d_in[6];
    const float* Wv   = (const float*)d_in[7];
    const float* bv   = (const float*)d_in[8];
    const float* Wo   = (const float*)d_in[9];
    const float* bo   = (const float*)d_in[10];
    const float* relk = (const float*)d_in[11];
    const float* relv = (const float*)d_in[12];

    float* out = (float*)d_out;
    char* w8 = (char*)d_ws;
    ushort* qb  = (ushort*)(w8);
    ushort* kb  = (ushort*)(w8 + (4u << 20));
    ushort* vb  = (ushort*)(w8 + (8u << 20));
    ushort* ab  = (ushort*)(w8 + (12u << 20));
    ushort* xb  = (ushort*)(w8 + (16u << 20));
    ushort* cb  = (ushort*)(w8 + (20u << 20));
    ushort* Wqb = (ushort*)(w8 + (24u << 20));
    ushort* Wkb = Wqb + 262144;
    ushort* Wvb = Wkb + 262144;
    ushort* Wob = Wvb + 262144;

    cvt_f2b<<<1024, 256, 0, stream>>>(x, xb, 262144);
    cvt_f2b<<<1024, 256, 0, stream>>>(c, cb, 262144);
    cvt_f2b<<<128, 256, 0, stream>>>(Wq, Wqb, 32768);
    cvt_f2b<<<128, 256, 0, stream>>>(Wk, Wkb, 32768);
    cvt_f2b<<<128, 256, 0, stream>>>(Wv, Wvb, 32768);
    cvt_f2b<<<128, 256, 0, stream>>>(Wo, Wob, 32768);

    dim3 ggrid(4096 / GB, D_ / GB);  // (64, 8)
    gemm_mfma<<<ggrid, 256, 0, stream>>>(xb, Wqb, bq, qb, 1);
    gemm_mfma<<<ggrid, 256, 0, stream>>>(cb, Wkb, bk, kb, 1);
    gemm_mfma<<<ggrid, 256, 0, stream>>>(cb, Wvb, bv, vb, 1);

    attn_tiled<<<dim3(T_ / TQ, B_ * H_), 256, 0, stream>>>(qb, kb, vb, am, relk, relv, ab);

    gemm_mfma<<<ggrid, 256, 0, stream>>>(ab, Wob, bo, (void*)out, 0);
}

// Round 4
// 185.354 us; speedup vs baseline: 6.2716x; 1.6153x over previous
//
#include <hip/hip_runtime.h>
#include <math.h>

#define D_   512
#define H_   4
#define KC   128
#define T_   1024
#define B_   4
#define NEG_ -10000.0f

typedef short bf16x8 __attribute__((ext_vector_type(8)));
typedef float f32x4  __attribute__((ext_vector_type(4)));

__device__ __forceinline__ ushort f2b_rne(float x) {
    unsigned u = __float_as_uint(x);
    u += 0x7fffu + ((u >> 16) & 1u);
    return (ushort)(u >> 16);
}

// ---------------------------------------------------------------------------
// fused fp32 -> bf16 converter for all 6 tensors (one launch)
// blocks: [0,1024) x, [1024,2048) c, [2048,2560) the 4 weights (128 each)
// ---------------------------------------------------------------------------
__global__ __launch_bounds__(256) void cvt_all(const float* __restrict__ x,
                                               const float* __restrict__ c,
                                               const float* __restrict__ w0,
                                               const float* __restrict__ w1,
                                               const float* __restrict__ w2,
                                               const float* __restrict__ w3,
                                               ushort* xo, ushort* co,
                                               ushort* o0, ushort* o1,
                                               ushort* o2, ushort* o3)
{
    const int blk = blockIdx.x;
    const float* src; ushort* dst; int base;
    if (blk < 1024)      { src = x; dst = xo; base = blk; }
    else if (blk < 2048) { src = c; dst = co; base = blk - 1024; }
    else {
        const int w = (blk - 2048) >> 7;
        base = (blk - 2048) & 127;
        src = (w == 0) ? w0 : (w == 1) ? w1 : (w == 2) ? w2 : w3;
        dst = (w == 0) ? o0 : (w == 1) ? o1 : (w == 2) ? o2 : o3;
    }
    const int i = base * 256 + threadIdx.x;
    const float4 a = ((const float4*)src)[2 * i];
    const float4 b = ((const float4*)src)[2 * i + 1];
    uint4 r;
    r.x = (unsigned)f2b_rne(a.x) | ((unsigned)f2b_rne(a.y) << 16);
    r.y = (unsigned)f2b_rne(a.z) | ((unsigned)f2b_rne(a.w) << 16);
    r.z = (unsigned)f2b_rne(b.x) | ((unsigned)f2b_rne(b.y) << 16);
    r.w = (unsigned)f2b_rne(b.z) | ((unsigned)f2b_rne(b.w) << 16);
    ((uint4*)dst)[i] = r;
}

// ---------------------------------------------------------------------------
// bf16 MFMA GEMM: C = A * W^T + bias
//  mode 0: fp32 row-major [M,512]
//  mode 1: bf16 head-split [B,H,T,KC]
//  mode 2: bf16 head-split TRANSPOSED [B,H,KC,T]  (for V)
// ---------------------------------------------------------------------------
#define GB 64
#define GK 32

__global__ __launch_bounds__(256) void gemm_mfma(const ushort* __restrict__ A,
                                                 const ushort* __restrict__ W,
                                                 const float* __restrict__ bias,
                                                 void* __restrict__ Cout, int mode)
{
    __shared__ __align__(16) ushort As[GB * GK];
    __shared__ __align__(16) ushort Bs[GB * GK];

    const int tid = threadIdx.x;
    const int m0 = blockIdx.x * GB;
    const int n0 = blockIdx.y * GB;
    const int lane = tid & 63;
    const int wid  = tid >> 6;
    const int wm = (wid >> 1) * 32;
    const int wn = (wid & 1) * 32;

    const int srow = tid >> 2;
    const int skb  = (tid & 3) * 8;
    const ushort* ga = A + (size_t)(m0 + srow) * D_ + skb;
    const ushort* gb = W + (size_t)(n0 + srow) * D_ + skb;

    f32x4 acc[2][2] = {};

    const int frow = lane & 15;
    const int fq   = lane >> 4;

    for (int k0 = 0; k0 < D_; k0 += GK) {
        __syncthreads();
        __builtin_amdgcn_global_load_lds(
            (const __attribute__((address_space(1))) void*)(ga + k0),
            (__attribute__((address_space(3))) void*)(As + tid * 8), 16, 0, 0);
        __builtin_amdgcn_global_load_lds(
            (const __attribute__((address_space(1))) void*)(gb + k0),
            (__attribute__((address_space(3))) void*)(Bs + tid * 8), 16, 0, 0);
        __syncthreads();

        bf16x8 af[2], bf[2];
#pragma unroll
        for (int mt = 0; mt < 2; mt++)
            af[mt] = *(const bf16x8*)(As + ((wm + mt * 16 + frow) * 4 + fq) * 8);
#pragma unroll
        for (int nt = 0; nt < 2; nt++)
            bf[nt] = *(const bf16x8*)(Bs + ((wn + nt * 16 + frow) * 4 + fq) * 8);
#pragma unroll
        for (int mt = 0; mt < 2; mt++)
#pragma unroll
            for (int nt = 0; nt < 2; nt++)
                acc[mt][nt] = __builtin_amdgcn_mfma_f32_16x16x32_bf16(
                    af[mt], bf[nt], acc[mt][nt], 0, 0, 0);
    }

#pragma unroll
    for (int mt = 0; mt < 2; mt++)
#pragma unroll
        for (int nt = 0; nt < 2; nt++) {
            const int n = n0 + wn + nt * 16 + frow;
            const float bn = bias[n];
            const int mb = m0 + wm + mt * 16 + fq * 4;
            if (mode == 2) {
                const int b = mb >> 10, t0 = mb & (T_ - 1);
                const int h = n >> 7, kc = n & (KC - 1);
                ushort4 pk;
                pk.x = f2b_rne(acc[mt][nt][0] + bn);
                pk.y = f2b_rne(acc[mt][nt][1] + bn);
                pk.z = f2b_rne(acc[mt][nt][2] + bn);
                pk.w = f2b_rne(acc[mt][nt][3] + bn);
                *(ushort4*)((ushort*)Cout +
                    ((size_t)((b * H_ + h) * KC + kc)) * T_ + t0) = pk;
            } else {
#pragma unroll
                for (int r = 0; r < 4; r++) {
                    const int m = mb + r;
                    const float val = acc[mt][nt][r] + bn;
                    if (mode == 1) {
                        const int b = m >> 10, t = m & (T_ - 1);
                        const int h = n >> 7, kc = n & (KC - 1);
                        ((ushort*)Cout)[((size_t)((b * H_ + h) * T_ + t)) * KC + kc] =
                            f2b_rne(val);
                    } else {
                        ((float*)Cout)[(size_t)m * D_ + n] = val;
                    }
                }
            }
        }
}

// ---------------------------------------------------------------------------
// MFMA flash attention. Block = 256 thr = 4 waves; (b,h) x 64-row Q tile.
// Wave w owns S/O rows [16w,16w+16). K/V col tiles of 64 over the band union.
// All LDS tiles bf16 with XOR chunk-swizzle: element (row,k) chunk k>>3 stored
// at chunk (k>>3)^(row&7)  ->  every fragment access <=2-way bank aliased.
// V pre-transposed globally to [bh][kc][t] so PV B-frags are ds_read_b128.
// ---------------------------------------------------------------------------
__global__ __launch_bounds__(256) void attn_mfma(const ushort* __restrict__ qg,
                                                 const ushort* __restrict__ kg,
                                                 const ushort* __restrict__ vtg,
                                                 const float* __restrict__ mask,
                                                 const float* __restrict__ relk,
                                                 const float* __restrict__ relv,
                                                 ushort* __restrict__ outp)
{
    const int bh = blockIdx.y;
    const int b  = bh >> 2;
    const int h  = bh & 3;
    const int i0 = blockIdx.x * 64;
    const int tid  = threadIdx.x;
    const int lane = tid & 63;
    const int wid  = tid >> 6;
    const int c_   = lane & 15;
    const int quad = lane >> 4;
    const int c7   = c_ & 7;
    const int row0 = 16 * wid;

    __shared__ __align__(16) ushort Qs[64 * 128];   // 16 KB
    __shared__ __align__(16) ushort Ks[64 * 128];   // 16 KB
    __shared__ __align__(16) ushort Vt[128 * 64];   // 16 KB  [ch][t]
    __shared__ __align__(16) ushort Ps[64 * 64];    //  8 KB
    __shared__ float relv_s[9 * 128];
    __shared__ float rlog[64][9];
    __shared__ float pdiag[64][9];
    __shared__ float lg[257];
    __shared__ float msk[64];
    __shared__ float rowm[64];

    const float scale = 0.08838834764831845f;  // 1/sqrt(128)

    // ---- one-time staging: Q tile (swizzled), tables ----
#pragma unroll
    for (int s = 0; s < 4; s++) {
        const int e = s * 256 + tid;
        const int r = e >> 4;
        const int c8 = e & 15;
        const uint4 val = *(const uint4*)(qg + ((size_t)(bh * T_ + i0 + r) * KC + c8 * 8));
        *(uint4*)(Qs + r * 128 + ((c8 ^ (r & 7)) * 8)) = val;
    }
    if (tid < 64) rowm[tid] = mask[b * T_ + i0 + tid];
    for (int e = tid; e < 576; e += 256) ((float*)pdiag)[e] = 0.f;
    for (int e = tid; e < 1152; e += 256) relv_s[e] = relv[e];
    for (int e = tid; e < 257; e += 256) lg[e] = log1pf((float)e);
    __syncthreads();

    // ---- rel-k logits: rlog[r][d] = scale * q[i0+r] . relk[d] ----
    {
        const int r = tid >> 2;
        const int kq4 = tid & 3;
        const int r7 = r & 7;
        float sacc[9];
#pragma unroll
        for (int d = 0; d < 9; d++) sacc[d] = 0.f;
        for (int kk = kq4 * 32; kk < kq4 * 32 + 32; kk++) {
            const float qv = __uint_as_float(
                ((unsigned)Qs[r * 128 + (((kk >> 3) ^ r7) * 8) + (kk & 7)]) << 16);
#pragma unroll
            for (int d = 0; d < 9; d++) sacc[d] += qv * relk[d * KC + kk];
        }
#pragma unroll
        for (int d = 0; d < 9; d++) {
            sacc[d] += __shfl_xor(sacc[d], 1);
            sacc[d] += __shfl_xor(sacc[d], 2);
            if (kq4 == 0) rlog[r][d] = sacc[d] * scale;
        }
    }

    float m_run[4], l_run[4];
    f32x4 acco[8] = {};
#pragma unroll
    for (int r4 = 0; r4 < 4; r4++) { m_run[r4] = -1e30f; l_run[r4] = 0.f; }

    const int cstart = (i0 - 256 > 0) ? (i0 - 256) : 0;
    const int cend   = (i0 + 64 + 256 < T_) ? (i0 + 64 + 256) : T_;
    const int ntl    = (cend - cstart) >> 6;

    for (int t = 0; t < ntl; t++) {
        const int j0 = cstart + t * 64;
        __syncthreads();  // prior tile's Vt/Ps reads complete

        // ---- stage K (row-swizzled) + Vt (ch-swizzled) + col mask ----
#pragma unroll
        for (int s = 0; s < 4; s++) {
            const int e = s * 256 + tid;
            const int r = e >> 4;
            const int c8 = e & 15;
            const uint4 kv = *(const uint4*)(kg + ((size_t)(bh * T_ + j0 + r) * KC + c8 * 8));
            *(uint4*)(Ks + r * 128 + ((c8 ^ (r & 7)) * 8)) = kv;
        }
#pragma unroll
        for (int s = 0; s < 4; s++) {
            const int e = s * 256 + tid;
            const int ch = e >> 3;
            const int k8 = e & 7;
            const uint4 vv = *(const uint4*)(vtg + ((size_t)(bh * KC + ch) * T_ + j0 + k8 * 8));
            *(uint4*)(Vt + ch * 64 + ((k8 ^ (ch & 7)) * 8)) = vv;
        }
        if (tid < 64) msk[tid] = mask[b * T_ + j0 + tid];
        __syncthreads();

        // ---- S = Q . K^T : 16 MFMAs per wave ----
        f32x4 accs[4] = {};
#pragma unroll
        for (int ks = 0; ks < 4; ks++) {
            const int sw = ((ks * 4 + quad) ^ c7) * 8;
            const bf16x8 aq = *(const bf16x8*)(Qs + (row0 + c_) * 128 + sw);
#pragma unroll
            for (int ct = 0; ct < 4; ct++) {
                const bf16x8 bk = *(const bf16x8*)(Ks + (ct * 16 + c_) * 128 + sw);
                accs[ct] = __builtin_amdgcn_mfma_f32_16x16x32_bf16(aq, bk, accs[ct], 0, 0, 0);
            }
        }

        // ---- online softmax on C-layout fragments ----
        float mskv[4];
#pragma unroll
        for (int ct = 0; ct < 4; ct++) mskv[ct] = msk[ct * 16 + c_];

        float alpha4[4];
#pragma unroll
        for (int r4 = 0; r4 < 4; r4++) {
            const int row = row0 + quad * 4 + r4;
            const float rm = rowm[row];
            const int dj = j0 - i0 + c_ - row;  // d at ct=0
            float sv[4];
            float mt = -3e38f;
#pragma unroll
            for (int ct = 0; ct < 4; ct++) {
                const int d = dj + ct * 16;
                const unsigned ad = (unsigned)((d < 0) ? -d : d);
                float s;
                if (rm != 0.f && mskv[ct] != 0.f && ad <= 256u) {
                    s = accs[ct][r4] * scale - lg[ad];
                    const unsigned dw = (unsigned)(d + 4);
                    if (dw <= 8u) s += rlog[row][dw];
                } else {
                    s = NEG_;
                }
                sv[ct] = s;
                mt = fmaxf(mt, s);
            }
            mt = fmaxf(mt, __shfl_xor(mt, 1));
            mt = fmaxf(mt, __shfl_xor(mt, 2));
            mt = fmaxf(mt, __shfl_xor(mt, 4));
            mt = fmaxf(mt, __shfl_xor(mt, 8));
            const float mnew = fmaxf(m_run[r4], mt);
            const float al = __expf(m_run[r4] - mnew);
            alpha4[r4] = al;
            m_run[r4] = mnew;

            const int row7 = row & 7;
            float lt = 0.f;
#pragma unroll
            for (int ct = 0; ct < 4; ct++) {
                const float p = __expf(sv[ct] - mnew);
                sv[ct] = p;
                lt += p;
                Ps[row * 64 + (((2 * ct + (c_ >> 3)) ^ row7) * 8) + c7] = f2b_rne(p);
            }
            lt += __shfl_xor(lt, 1);
            lt += __shfl_xor(lt, 2);
            lt += __shfl_xor(lt, 4);
            lt += __shfl_xor(lt, 8);
            l_run[r4] = l_run[r4] * al + lt;

            // pdiag: rescale (c_==0 lane) then adds — same-wave ds ops, in order
            if (c_ == 0) {
#pragma unroll
                for (int dd = 0; dd < 9; dd++) pdiag[row][dd] *= al;
            }
#pragma unroll
            for (int ct = 0; ct < 4; ct++) {
                const int d = dj + ct * 16;
                const unsigned dw = (unsigned)(d + 4);
                if (dw <= 8u) pdiag[row][dw] += sv[ct];
            }
        }

        // ---- O *= alpha ; PV: 16 MFMAs per wave ----
#pragma unroll
        for (int nt = 0; nt < 8; nt++)
#pragma unroll
            for (int r4 = 0; r4 < 4; r4++) acco[nt][r4] *= alpha4[r4];

        __syncthreads();  // Ps visible (and keeps waves in phase)

#pragma unroll
        for (int kt = 0; kt < 2; kt++) {
            const int sw = ((kt * 4 + quad) ^ c7) * 8;
            const bf16x8 ap = *(const bf16x8*)(Ps + (row0 + c_) * 64 + sw);
#pragma unroll
            for (int nt = 0; nt < 8; nt++) {
                const bf16x8 bv = *(const bf16x8*)(Vt + (nt * 16 + c_) * 64 + sw);
                acco[nt] = __builtin_amdgcn_mfma_f32_16x16x32_bf16(ap, bv, acco[nt], 0, 0, 0);
            }
        }
    }

    __syncthreads();

    // ---- epilogue: rel-v via pdiag, normalize, store bf16 [b,t,h,kc] ----
#pragma unroll
    for (int r4 = 0; r4 < 4; r4++) {
        const int row = row0 + quad * 4 + r4;
        const int i = i0 + row;
        const float invl = 1.f / l_run[r4];
        float pd[9];
#pragma unroll
        for (int dd = 0; dd < 9; dd++) {
            const int j = i + dd - 4;
            pd[dd] = (j >= 0 && j < T_) ? pdiag[row][dd] : 0.f;
        }
        ushort* ob = outp + ((size_t)(b * T_ + i) * H_ + h) * KC;
#pragma unroll
        for (int nt = 0; nt < 8; nt++) {
            const int col = nt * 16 + c_;
            float o = acco[nt][r4];
#pragma unroll
            for (int dd = 0; dd < 9; dd++) o += pd[dd] * relv_s[dd * 128 + col];
            ob[col] = f2b_rne(o * invl);
        }
    }
}

// ---------------------------------------------------------------------------
extern "C" void kernel_launch(void* const* d_in, const int* in_sizes, int n_in,
                              void* d_out, int out_size, void* d_ws, size_t ws_size,
                              hipStream_t stream)
{
    const float* x    = (const float*)d_in[0];
    const float* c    = (const float*)d_in[1];
    const float* am   = (const float*)d_in[2];
    const float* Wq   = (const float*)d_in[3];
    const float* bq   = (const float*)d_in[4];
    const float* Wk   = (const float*)d_in[5];
    const float* bk   = (const float*)d_in[6];
    const float* Wv   = (const float*)d_in[7];
    const float* bv   = (const float*)d_in[8];
    const float* Wo   = (const float*)d_in[9];
    const float* bo   = (const float*)d_in[10];
    const float* relk = (const float*)d_in[11];
    const float* relv = (const float*)d_in[12];

    float* out = (float*)d_out;
    char* w8 = (char*)d_ws;
    ushort* qb  = (ushort*)(w8);
    ushort* kb  = (ushort*)(w8 + (4u << 20));
    ushort* vtb = (ushort*)(w8 + (8u << 20));   // [B,H,KC,T]
    ushort* ab  = (ushort*)(w8 + (12u << 20));
    ushort* xb  = (ushort*)(w8 + (16u << 20));
    ushort* cb  = (ushort*)(w8 + (20u << 20));
    ushort* Wqb = (ushort*)(w8 + (24u << 20));
    ushort* Wkb = Wqb + 262144;
    ushort* Wvb = Wkb + 262144;
    ushort* Wob = Wvb + 262144;

    cvt_all<<<2560, 256, 0, stream>>>(x, c, Wq, Wk, Wv, Wo, xb, cb, Wqb, Wkb, Wvb, Wob);

    dim3 ggrid(4096 / GB, D_ / GB);  // (64, 8)
    gemm_mfma<<<ggrid, 256, 0, stream>>>(xb, Wqb, bq, qb, 1);
    gemm_mfma<<<ggrid, 256, 0, stream>>>(cb, Wkb, bk, kb, 1);
    gemm_mfma<<<ggrid, 256, 0, stream>>>(cb, Wvb, bv, vtb, 2);

    attn_mfma<<<dim3(16, 16), 256, 0, stream>>>(qb, kb, vtb, am, relk, relv, ab);

    gemm_mfma<<<ggrid, 256, 0, stream>>>(ab, Wob, bo, (void*)out, 0);
}